// Round 7
// baseline (62.199 us; speedup 1.0000x reference)
//
#include <hip/hip_runtime.h>
#include <math.h>

#define NN 4096
#define RCAP 256          // per-row bucket capacity (mean 80, max ~130)
#define CPAD 16           // counter stride in ints: one counter per 64B line
#define HS 512            // per-row LDS hash slots (>= RCAP, load <= 50%)
#define NBC 128           // colsum partial blocks

// mysign(|v|) - 0.5 with reference-faithful overflow: e=inf -> NaN
__device__ __forceinline__ float smh(float v) {
    float e = expf(6.0f * fabsf(v));
    return 0.5f * (e - 1.0f) / (e + 1.0f);
}

// Zero the row counters ourselves: the rocclr fillBuffer kernel for small
// fills is latency-bound (~40us for 256KB, measured round 6). 64 blocks x
// 256 threads x 16B = 256KB exactly.
__global__ __launch_bounds__(256) void zero_k(float4* __restrict__ p) {
    p[blockIdx.x * 256 + threadIdx.x] = make_float4(0.f, 0.f, 0.f, 0.f);
}

// Bucket all records by row. Payload is a plain (non-atomic) 16B store;
// only the position counter is atomic (padded: 1 counter per cache line).
__global__ __launch_bounds__(256) void bucket_k(
    const int2* __restrict__ edges, const float* __restrict__ weights,
    const float* __restrict__ stat, const int2* __restrict__ edges_c,
    const float* __restrict__ grdt, int* __restrict__ row_cnt,
    float4* __restrict__ rowbuf, int E, int EC) {
    int i = blockIdx.x * 256 + threadIdx.x;
    int2 rc; float f0, f1 = 0.f; int isC;
    if (i < E) {
        rc = edges[i]; f0 = stat[i]; f1 = weights[i]; isC = 0;
    } else if (i < E + EC) {
        int j = i - E;
        rc = edges_c[j]; f0 = grdt[j]; isC = 1;
    } else return;
    int pos = atomicAdd(&row_cnt[rc.x * CPAD], 1);
    if (pos < RCAP) {
        float4 rec;
        rec.x = __int_as_float((rc.y << 1) | isC);
        rec.y = f0;      // stat (A) or grdt (B)
        rec.z = f1;      // weight (W) or unused
        rec.w = 0.f;
        rowbuf[rc.x * RCAP + pos] = rec;
    }
}

// One block per row: small LDS hash coalesces duplicate cells (scatter-add
// semantics like the reference), then sweep the 512 slots: v = B*(A-1)+A*W,
// emit compact (col,v) row-CSR and block-reduced nout. No global atomics.
__global__ __launch_bounds__(128) void coalesce_k(
    const int* __restrict__ row_cnt, const float4* __restrict__ rowbuf,
    int2* __restrict__ out_rc, int* __restrict__ cnt2,
    float* __restrict__ nout) {
    __shared__ int hkey[HS];
    __shared__ float hA[HS], hW[HS], hB[HS];
    __shared__ int s_n;
    __shared__ float red[2];
    const int r = blockIdx.x;
    const int tid = threadIdx.x;
    for (int i = tid; i < HS; i += 128) {
        hkey[i] = -1; hA[i] = 0.f; hW[i] = 0.f; hB[i] = 0.f;
    }
    if (tid == 0) s_n = 0;
    __syncthreads();
    int cnt = row_cnt[r * CPAD];
    if (cnt > RCAP) cnt = RCAP;
    for (int i = tid; i < cnt; i += 128) {
        float4 rec = rowbuf[r * RCAP + i];
        int ct = __float_as_int(rec.x);
        int c = ct >> 1;
        int slot = (int)(((unsigned)c * 2654435761u) >> 23) & (HS - 1);
        while (true) {
            int prev = atomicCAS(&hkey[slot], -1, c);
            if (prev == -1 || prev == c) break;
            slot = (slot + 1) & (HS - 1);
        }
        if (ct & 1) {
            atomicAdd(&hB[slot], rec.y);
        } else {
            atomicAdd(&hA[slot], rec.y);
            atomicAdd(&hW[slot], rec.z);
        }
    }
    __syncthreads();
    float nacc = 0.f;
#pragma unroll
    for (int k = 0; k < HS / 128; ++k) {
        int s = k * 128 + tid;
        int c = hkey[s];
        if (c != -1) {
            float a = hA[s], w = hW[s], b = hB[s];
            float v = b * (a - 1.0f) + a * w;
            if (v != 0.0f) {                   // zero cells: 0 to all sums
                nacc += smh(v);                // NaN propagates like ref
                int pos = atomicAdd(&s_n, 1);  // LDS counter, cheap
                out_rc[r * RCAP + pos] = make_int2(c, __float_as_int(v));
            }
        }
    }
    for (int off = 32; off > 0; off >>= 1) nacc += __shfl_down(nacc, off, 64);
    if ((tid & 63) == 0) red[tid >> 6] = nacc;
    __syncthreads();
    if (tid == 0) {
        nout[r] = red[0] + red[1];
        cnt2[r] = s_n;
    }
}

// Column sums from the compact CSR: block-level LDS accumulators for
// g (col sum of v) and nin (col sum of smh), flushed as one partial
// per block. Wave-per-row reads are coalesced (64 x 8B contiguous).
__global__ __launch_bounds__(256) void colsum_k(
    const int* __restrict__ cnt2, const int2* __restrict__ out_rc,
    float* __restrict__ part) {
    __shared__ float sg[NN], sn2[NN];
    for (int i = threadIdx.x; i < NN; i += 256) { sg[i] = 0.f; sn2[i] = 0.f; }
    __syncthreads();
    const int wv = threadIdx.x >> 6, lane = threadIdx.x & 63;
    const int rows_per_blk = NN / NBC;             // 32
    const int r0 = blockIdx.x * rows_per_blk + wv * (rows_per_blk / 4);
#pragma unroll
    for (int j = 0; j < rows_per_blk / 4; ++j) {   // 8 rows per wave
        int r = r0 + j;
        int cnt = cnt2[r];
        for (int i = lane; i < cnt; i += 64) {
            int2 rec = out_rc[r * RCAP + i];
            float v = __int_as_float(rec.y);
            atomicAdd(&sg[rec.x], v);
            atomicAdd(&sn2[rec.x], smh(v));
        }
    }
    __syncthreads();
    float* myp = part + (size_t)blockIdx.x * (2 * NN);
    for (int i = threadIdx.x; i < NN; i += 256) {
        myp[i] = sg[i];
        myp[NN + i] = sn2[i];
    }
}

// Fold partials -> good. good = clip(g/Nin,-1,1), NaN-propagating;
// Nin baseline 2048 = 0.5 * 4096 (mysign(0)=0.5).
__global__ __launch_bounds__(256) void reduce_good_k(
    const float* __restrict__ part, float* __restrict__ good_buf,
    float* __restrict__ good_out) {
    int c = blockIdx.x * 256 + threadIdx.x;
    float g = 0.f, nin = 0.f;
    for (int b = 0; b < NBC; ++b) {
        const float* p = part + (size_t)b * (2 * NN);
        g += p[c];
        nin += p[NN + c];
    }
    float Nin = 2048.0f + nin;
    float gd = 1.0f;
    if (Nin != 0.0f) {
        float x = g / Nin;
        gd = x < -1.0f ? -1.0f : (x > 1.0f ? 1.0f : x);  // NaN stays NaN
    }
    good_buf[c] = gd;
    good_out[c] = gd;
}

// Wave per row over the compact (col,v) list (v != 0 mask is implicit);
// last block does the targets gsum.
__global__ __launch_bounds__(256) void fair_k(
    const int* __restrict__ cnt2, const int2* __restrict__ out_rc,
    const float* __restrict__ nout, const float* __restrict__ good_buf,
    const int* __restrict__ targets, int T, float* __restrict__ out) {
    if (blockIdx.x < NN / 4) {
        int wv = threadIdx.x >> 6, lane = threadIdx.x & 63;
        int r = blockIdx.x * 4 + wv;
        int cnt = cnt2[r];
        float f = 0.f;
        for (int i = lane; i < cnt; i += 64) {
            int2 rec = out_rc[r * RCAP + i];
            float v = __int_as_float(rec.y);
            f += 1.0f - 0.5f * fabsf(v - good_buf[rec.x]);
        }
        for (int off = 32; off > 0; off >>= 1) f += __shfl_down(f, off, 64);
        if (lane == 0) {
            float Nout = 2048.0f + nout[r];
            float fair = 1.0f;
            if (Nout != 0.0f) {
                float x = f / Nout;
                fair = x < 0.0f ? 0.0f : (x > 1.0f ? 1.0f : x);  // NaN stays
            }
            out[1 + r] = fair;
        }
    } else {
        float s = 0.f;
        for (int i = threadIdx.x; i < T; i += 256) {
            float gt = good_buf[targets[i]];
            s += (gt == gt) ? gt : 0.0f;   // NaN -> 0
        }
        for (int off = 32; off > 0; off >>= 1) s += __shfl_down(s, off, 64);
        __shared__ float lds[4];
        int lane = threadIdx.x & 63, w = threadIdx.x >> 6;
        if (lane == 0) lds[w] = s;
        __syncthreads();
        if (threadIdx.x == 0) out[0] = lds[0] + lds[1] + lds[2] + lds[3];
    }
}

extern "C" void kernel_launch(void* const* d_in, const int* in_sizes, int n_in,
                              void* d_out, int out_size, void* d_ws, size_t ws_size,
                              hipStream_t stream) {
    const int2*  edges   = (const int2*)d_in[0];
    const float* weights = (const float*)d_in[1];
    const float* stat    = (const float*)d_in[2];
    const int2*  edges_c = (const int2*)d_in[3];
    const float* grdt    = (const float*)d_in[4];
    const int*   targets = (const int*)d_in[5];
    const int E  = in_sizes[1];
    const int EC = in_sizes[4];
    const int T  = in_sizes[5];
    float* out = (float*)d_out;

    int*    row_cnt  = (int*)d_ws;                          // NN*CPAD
    int*    cnt2     = row_cnt + NN * CPAD;                 // NN
    float*  nout     = (float*)(cnt2 + NN);                 // NN
    float*  good_buf = nout + NN;                           // NN
    float4* rowbuf   = (float4*)(good_buf + NN);            // NN*RCAP float4
    int2*   out_rc   = (int2*)(rowbuf + (size_t)NN * RCAP); // NN*RCAP int2
    float*  part     = (float*)(out_rc + (size_t)NN * RCAP);// NBC*2*NN

    // zero row_cnt: NN*CPAD ints = 256KB = 64 blocks * 256 threads * 16B
    zero_k<<<NN * CPAD / (256 * 4), 256, 0, stream>>>((float4*)row_cnt);

    bucket_k<<<(E + EC + 255) / 256, 256, 0, stream>>>(
        edges, weights, stat, edges_c, grdt, row_cnt, rowbuf, E, EC);

    coalesce_k<<<NN, 128, 0, stream>>>(row_cnt, rowbuf, out_rc, cnt2, nout);

    colsum_k<<<NBC, 256, 0, stream>>>(cnt2, out_rc, part);

    reduce_good_k<<<NN / 256, 256, 0, stream>>>(part, good_buf, out + 1 + NN);

    fair_k<<<NN / 4 + 1, 256, 0, stream>>>(cnt2, out_rc, nout, good_buf,
                                           targets, T, out);
}